// Round 7
// baseline (514.165 us; speedup 1.0000x reference)
//
#include <hip/hip_runtime.h>
#include <cstdint>

#define NNODES 50000
#define NEDGES 800000
#define ETOT   (NEDGES + NNODES)
#define HEADS 4
#define CH 64
#define HC 256
#define INDIM 256
#define OUTDIM 64
#define NEG_SLOPE 0.2f
#define BN_EPS 1e-5f
#define NB 128   // bn_stats partial blocks

typedef unsigned short u16;
typedef unsigned int u32;
typedef __attribute__((ext_vector_type(8))) short short8;
typedef __attribute__((ext_vector_type(8))) unsigned short ushort8v;
typedef __attribute__((ext_vector_type(4))) float floatx4;

__device__ inline float bf2f(u16 u) {
    union { unsigned int i; float f; } c;
    c.i = ((unsigned int)u) << 16;
    return c.f;
}
__device__ inline u16 f2bf(float f) {
    union { float f; unsigned int i; } c;
    c.f = f;
    unsigned int u = c.i + 0x7fff + ((c.i >> 16) & 1);
    return (u16)(u >> 16);
}
// permuted position of logical channel b (within-head 16x4 transpose)
__device__ __host__ inline int pos256(int b) {
    int h = b >> 6, c = b & 63;
    return h * 64 + (c & 15) * 4 + (c >> 4);
}
__device__ inline void async16(u16* lds, const u16* g) {
    __builtin_amdgcn_global_load_lds(
        (const __attribute__((address_space(1))) unsigned int*)g,
        (__attribute__((address_space(3))) unsigned int*)lds,
        16, 0, 0);
}

// ---------------- CSR build (dst-sorted) ----------------

__global__ void hist_kernel(const int* __restrict__ ei, int* __restrict__ cnt) {
    int t = blockIdx.x * blockDim.x + threadIdx.x;
    if (t >= ETOT) return;
    int d = (t < NEDGES) ? ei[NEDGES + t] : (t - NEDGES);
    atomicAdd(&cnt[d], 1);
}

__global__ void scan1_kernel(const int* __restrict__ cnt, int* __restrict__ row_off,
                             int* __restrict__ blockSums) {
    __shared__ int tsum[256];
    const int tid = threadIdx.x;
    const int base = blockIdx.x * 4096 + tid * 16;
    int local[16];
    int run = 0;
#pragma unroll
    for (int i = 0; i < 16; ++i) {
        int idx = base + i;
        int v = (idx < NNODES) ? cnt[idx] : 0;
        local[i] = run;
        run += v;
    }
    tsum[tid] = run;
    __syncthreads();
    for (int d = 1; d < 256; d <<= 1) {
        int v = (tid >= d) ? tsum[tid - d] : 0;
        __syncthreads();
        tsum[tid] += v;
        __syncthreads();
    }
    int excl = (tid == 0) ? 0 : tsum[tid - 1];
#pragma unroll
    for (int i = 0; i < 16; ++i) {
        int idx = base + i;
        if (idx < NNODES) row_off[idx] = excl + local[i];
    }
    if (tid == 0) blockSums[blockIdx.x] = tsum[255];
}

__global__ void scan2_kernel(int* __restrict__ row_off, const int* __restrict__ blockSums,
                             int* __restrict__ nxt) {
    __shared__ int sprefix;
    if (threadIdx.x == 0) {
        int p = 0;
        for (int b = 0; b < (int)blockIdx.x; ++b) p += blockSums[b];
        sprefix = p;
    }
    __syncthreads();
    int prefix = sprefix;
    int base = blockIdx.x * 4096 + threadIdx.x * 16;
#pragma unroll
    for (int i = 0; i < 16; ++i) {
        int idx = base + i;
        if (idx < NNODES) {
            int v = row_off[idx] + prefix;
            row_off[idx] = v;
            nxt[idx] = v;
        }
    }
    if (blockIdx.x == 0 && threadIdx.x == 0) row_off[NNODES] = ETOT;
}

__global__ void fill_csr_kernel(const int* __restrict__ ei, int* __restrict__ nxt,
                                int* __restrict__ csr_src, int* __restrict__ csr_dst) {
    int t = blockIdx.x * blockDim.x + threadIdx.x;
    if (t >= ETOT) return;
    int s, d;
    if (t < NEDGES) { s = ei[t]; d = ei[NEDGES + t]; }
    else            { s = d = t - NEDGES; }
    int pos = atomicAdd(&nxt[d], 1);
    csr_src[pos] = s;
    csr_dst[pos] = d;
}

// ---------------- weight cast: W [K][Ncols] fp32 -> Wt [Ncols][K] bf16 ----------------

__global__ void wcast_kernel(const float* __restrict__ W, u16* __restrict__ Wt,
                             int K, int Ncols) {
    int t = blockIdx.x * blockDim.x + threadIdx.x;
    if (t >= K * Ncols) return;
    int k = t / Ncols, n = t - k * Ncols;
    Wt[n * K + k] = f2bf(W[t]);
}

// ---------------- bf16 MFMA GEMM + fused alpha + permuted bf16 output ----------------
// C[M,256] = A[M,K] @ Bt[256,K]^T (+bias). Output xhp: bf16 table in PERMUTED channel
// order (pos256) + per-head alpha_src/alpha_dst.
// AF32: A is fp32 (converted in staging); else A is bf16 (async global->LDS).

template <bool AF32>
__global__ __launch_bounds__(256)
void gemm_gat_kernel(const void* __restrict__ Ap, const u16* __restrict__ Bt,
                     const float* __restrict__ bias,
                     const float* __restrict__ att_s, const float* __restrict__ att_d,
                     u16* __restrict__ xhp, float* __restrict__ asrc,
                     float* __restrict__ adst, int M, int K) {
    __shared__ u16 As[128 * 32];
    __shared__ u16 Bs[128 * 32];
    const int tid = threadIdx.x;
    const int wave = tid >> 6, lane = tid & 63;
    const int q15 = lane & 15, quad = lane >> 4;
    const int rowBase = blockIdx.y * 128;
    const int colBase = blockIdx.x * 128;
    const int waveM = (wave >> 1) * 64, waveN = (wave & 1) * 64;
    const int head = blockIdx.x * 2 + (wave & 1);

    floatx4 acc[4][4];
    floatx4 zero = {0.f, 0.f, 0.f, 0.f};
#pragma unroll
    for (int i = 0; i < 4; ++i)
#pragma unroll
        for (int j = 0; j < 4; ++j) acc[i][j] = zero;

    for (int kt = 0; kt < K; kt += 32) {
        if constexpr (AF32) {
            const float* A32 = (const float*)Ap;
#pragma unroll
            for (int rnd = 0; rnd < 4; ++rnd) {
                int slot = rnd * 256 + tid;       // 1024 slots = 128 rows x 8 col-groups
                int r = slot >> 3, c4 = (slot & 7) * 4;
                int ar = rowBase + r; if (ar >= M) ar = M - 1;
                float4 fv = *(const float4*)&A32[(size_t)ar * K + kt + c4];
                ushort4 o;
                o.x = f2bf(fv.x); o.y = f2bf(fv.y); o.z = f2bf(fv.z); o.w = f2bf(fv.w);
                *(ushort4*)&As[r * 32 + c4] = o;
            }
#pragma unroll
            for (int q = 0; q < 2; ++q) {
                int e8 = (wave * 2 + q) * 64 + lane;
                int r = e8 >> 2, c = (e8 & 3) * 8;
                async16(&Bs[(wave * 2 + q) * 512], &Bt[(size_t)(colBase + r) * K + kt + c]);
            }
        } else {
            const u16* A16 = (const u16*)Ap;
#pragma unroll
            for (int q = 0; q < 2; ++q) {
                int e8 = (wave * 2 + q) * 64 + lane;
                int r = e8 >> 2, c = (e8 & 3) * 8;
                int ar = rowBase + r; if (ar >= M) ar = M - 1;
                async16(&As[(wave * 2 + q) * 512], &A16[(size_t)ar * K + kt + c]);
                async16(&Bs[(wave * 2 + q) * 512], &Bt[(size_t)(colBase + r) * K + kt + c]);
            }
        }
        __syncthreads();

        short8 af[4], bfr[4];
#pragma unroll
        for (int i = 0; i < 4; ++i)
            af[i] = *(const short8*)&As[(waveM + i * 16 + q15) * 32 + quad * 8];
#pragma unroll
        for (int j = 0; j < 4; ++j)
            bfr[j] = *(const short8*)&Bs[(waveN + j * 16 + q15) * 32 + quad * 8];
#pragma unroll
        for (int i = 0; i < 4; ++i)
#pragma unroll
            for (int j = 0; j < 4; ++j)
                acc[i][j] = __builtin_amdgcn_mfma_f32_16x16x32_bf16(af[i], bfr[j], acc[i][j], 0, 0, 0);
        __syncthreads();
    }

    float bv[4], atsv[4], atdv[4];
#pragma unroll
    for (int j = 0; j < 4; ++j) {
        int gcol = colBase + waveN + j * 16 + q15;
        bv[j] = bias ? bias[gcol] : 0.f;
        int hc = head * CH + j * 16 + q15;
        atsv[j] = att_s[hc];
        atdv[j] = att_d[hc];
    }
    const int pbase = head * 64 + q15 * 4;   // permuted ushort index within row

#pragma unroll
    for (int i = 0; i < 4; ++i) {
#pragma unroll
        for (int rr = 0; rr < 4; ++rr) {
            int grow = rowBase + waveM + i * 16 + quad * 4 + rr;
            float v[4];
#pragma unroll
            for (int j = 0; j < 4; ++j) v[j] = acc[i][j][rr] + bv[j];
            // fused alpha: dot over this head's 64 cols (4 regs x 16 lanes in quad)
            float s = v[0] * atsv[0] + v[1] * atsv[1] + v[2] * atsv[2] + v[3] * atsv[3];
            float d = v[0] * atdv[0] + v[1] * atdv[1] + v[2] * atdv[2] + v[3] * atdv[3];
#pragma unroll
            for (int off = 1; off <= 8; off <<= 1) {
                s += __shfl_xor(s, off, 64);
                d += __shfl_xor(d, off, 64);
            }
            ushort4 o;
            o.x = f2bf(v[0]); o.y = f2bf(v[1]); o.z = f2bf(v[2]); o.w = f2bf(v[3]);
            if (grow < M) {
                *(ushort4*)&xhp[(size_t)grow * HC + pbase] = o;
                if (q15 == 0) {
                    asrc[grow * 4 + head] = s;
                    adst[grow * 4 + head] = d;
                }
            }
        }
    }
}

// ---------------- per-edge softmax weights (unnormalized, bf16): w4b[e][h] ----------------

__global__ void wedge_kernel(const int* __restrict__ csr_src, const int* __restrict__ csr_dst,
                             const float* __restrict__ asrc, const float* __restrict__ adst,
                             u16* __restrict__ w4b) {
    int e = blockIdx.x * blockDim.x + threadIdx.x;
    if (e >= ETOT) return;
    int s = csr_src[e], d = csr_dst[e];
    float4 a = *(const float4*)&asrc[s * 4];
    float4 b = *(const float4*)&adst[d * 4];
    ushort4 r;
    float v;
    v = a.x + b.x; v = v > 0.f ? v : NEG_SLOPE * v; r.x = f2bf(__expf(v));
    v = a.y + b.y; v = v > 0.f ? v : NEG_SLOPE * v; r.y = f2bf(__expf(v));
    v = a.z + b.z; v = v > 0.f ? v : NEG_SLOPE * v; r.z = f2bf(__expf(v));
    v = a.w + b.w; v = v > 0.f ? v : NEG_SLOPE * v; r.w = f2bf(__expf(v));
    *(ushort4*)&w4b[(size_t)e * 4] = r;
}

// ---------------- fused aggregate over permuted bf16 table ----------------
// 1 wave = 1 dst node. Lane l (h=l>>4, c16=l&15) reads ushort4 at row*256+h*64+c16*4
// covering logical channels h*64 + j*16 + c16, j=0..3. Output stays PERMUTED (ushort4).

__global__ __launch_bounds__(256)
void aggregate_kernel(const int* __restrict__ row_off, const int* __restrict__ csr_src,
                      const u16* __restrict__ w4b, const u16* __restrict__ xhp,
                      const float* __restrict__ bias, u16* __restrict__ out) {
    const int g = threadIdx.x >> 6;
    const int lane = threadIdx.x & 63;
    const int d = blockIdx.x * 4 + g;
    const int h = lane >> 4;
    const int c16 = lane & 15;
    const int poff = h * 64 + c16 * 4;
    const int start = row_off[d], end = row_off[d + 1];
    float a0 = 0.f, a1 = 0.f, a2 = 0.f, a3 = 0.f, den = 0.f;
    int e = start;
    for (; e + 3 < end; e += 4) {
        int s0 = csr_src[e], s1 = csr_src[e + 1], s2 = csr_src[e + 2], s3 = csr_src[e + 3];
        float w0 = bf2f(w4b[(size_t)e * 4 + h]);
        float w1 = bf2f(w4b[(size_t)(e + 1) * 4 + h]);
        float w2 = bf2f(w4b[(size_t)(e + 2) * 4 + h]);
        float w3 = bf2f(w4b[(size_t)(e + 3) * 4 + h]);
        ushort4 x0 = *(const ushort4*)&xhp[(size_t)s0 * HC + poff];
        ushort4 x1 = *(const ushort4*)&xhp[(size_t)s1 * HC + poff];
        ushort4 x2 = *(const ushort4*)&xhp[(size_t)s2 * HC + poff];
        ushort4 x3 = *(const ushort4*)&xhp[(size_t)s3 * HC + poff];
        den += (w0 + w1) + (w2 + w3);
        a0 += w0 * bf2f(x0.x) + w1 * bf2f(x1.x) + w2 * bf2f(x2.x) + w3 * bf2f(x3.x);
        a1 += w0 * bf2f(x0.y) + w1 * bf2f(x1.y) + w2 * bf2f(x2.y) + w3 * bf2f(x3.y);
        a2 += w0 * bf2f(x0.z) + w1 * bf2f(x1.z) + w2 * bf2f(x2.z) + w3 * bf2f(x3.z);
        a3 += w0 * bf2f(x0.w) + w1 * bf2f(x1.w) + w2 * bf2f(x2.w) + w3 * bf2f(x3.w);
    }
    for (; e < end; ++e) {
        int s0 = csr_src[e];
        float w = bf2f(w4b[(size_t)e * 4 + h]);
        ushort4 x0 = *(const ushort4*)&xhp[(size_t)s0 * HC + poff];
        den += w;
        a0 += w * bf2f(x0.x);
        a1 += w * bf2f(x0.y);
        a2 += w * bf2f(x0.z);
        a3 += w * bf2f(x0.w);
    }
    float inv = 1.f / (den + 1e-16f);
    const int ch0 = h * 64 + c16;   // logical channel of o.x; +16/+32/+48 for y/z/w
    ushort4 o;
    o.x = f2bf(a0 * inv + bias[ch0 +  0]);
    o.y = f2bf(a1 * inv + bias[ch0 + 16]);
    o.z = f2bf(a2 * inv + bias[ch0 + 32]);
    o.w = f2bf(a3 * inv + bias[ch0 + 48]);
    *(ushort4*)&out[(size_t)d * HC + poff] = o;   // permuted, coalesced
}

// ---------------- BatchNorm stats over permuted buffer (positional) ----------------

__global__ __launch_bounds__(256)
void bn_stats_kernel(const u16* __restrict__ x, float* __restrict__ part) {
    const int tid = threadIdx.x;
    float s[8] = {}, s2[8] = {};
    const size_t total = (size_t)NNODES * HC;
    const size_t stride = (size_t)NB * 256 * 8;
    for (size_t f = ((size_t)blockIdx.x * 256 + tid) * 8; f < total; f += stride) {
        ushort8v v = *(const ushort8v*)&x[f];
#pragma unroll
        for (int i = 0; i < 8; ++i) {
            float t = bf2f(v[i]);
            s[i] += t;
            s2[i] += t * t;
        }
    }
#pragma unroll
    for (int i = 0; i < 8; ++i) {
        s[i] += __shfl_xor(s[i], 32, 64);
        s2[i] += __shfl_xor(s2[i], 32, 64);
    }
    __shared__ float red[4][512];
    const int wave = tid >> 6, lane = tid & 63;
    if (lane < 32) {
#pragma unroll
        for (int i = 0; i < 8; ++i) {
            red[wave][lane * 8 + i] = s[i];
            red[wave][256 + lane * 8 + i] = s2[i];
        }
    }
    __syncthreads();
    for (int j = tid; j < 512; j += 256)
        part[(size_t)blockIdx.x * 512 + j] = red[0][j] + red[1][j] + red[2][j] + red[3][j];
}

// ---------------- BN fold (permutation-aware) ----------------
// blocks 0..255 (logical channel b): stats live at position pos256(b); folded weight
// row goes to K-position pos256(b) (matching the permuted A layout).
// block 256: folded bias (logical indexing throughout).

__global__ __launch_bounds__(256)
void fold_kernel(const float* __restrict__ W, const float* __restrict__ part,
                 const float* __restrict__ g, const float* __restrict__ beta,
                 const float* __restrict__ baseBias,
                 u16* __restrict__ Wt, float* __restrict__ biasOut, int Ncols) {
    __shared__ float sh[256];
    __shared__ float stat2[2];
    const int b = blockIdx.x;
    const int tid = threadIdx.x;
    if (b < 256) {
        const int p = pos256(b);
        const int wave = tid >> 6, lane = tid & 63;
        if (wave < 2) {
            int off = wave * 256;
            float v = part[(size_t)lane * 512 + off + p] + part[(size_t)(lane + 64) * 512 + off + p];
#pragma unroll
            for (int o = 1; o <= 32; o <<= 1) v += __shfl_xor(v, o, 64);
            if (lane == 0) stat2[wave] = v;
        }
        __syncthreads();
        float mu = stat2[0] * (1.f / NNODES);
        float var = stat2[1] * (1.f / NNODES) - mu * mu;
        float rg = rsqrtf(var + BN_EPS) * g[b];
        for (int n = tid; n < Ncols; n += 256)
            Wt[n * 256 + p] = f2bf(W[b * Ncols + n] * rg);
    } else {
        // logical channel tid: stats from pos256(tid)
        const int p = pos256(tid);
        float sum = 0.f, sq = 0.f;
        for (int k = 0; k < NB; ++k) {
            sum += part[(size_t)k * 512 + p];
            sq += part[(size_t)k * 512 + 256 + p];
        }
        float mu = sum * (1.f / NNODES);
        float var = sq * (1.f / NNODES) - mu * mu;
        float rg = rsqrtf(var + BN_EPS) * g[tid];
        sh[tid] = beta[tid] - mu * rg;
        __syncthreads();
        if (tid < Ncols) {
            float acc = baseBias ? baseBias[tid] : 0.f;
            for (int k = 0; k < 256; ++k) acc += sh[k] * W[k * Ncols + tid];
            biasOut[tid] = acc;
        }
    }
}

// ---------------- fused final GEMM (M x 64, K=256) + bias + log_softmax ----------------
// 128 rows per block (4 waves x 32 rows), grid = ceil(M/128).

__global__ __launch_bounds__(256)
void final_ls_kernel(const u16* __restrict__ A, const u16* __restrict__ Bt,
                     const float* __restrict__ bias,
                     float* __restrict__ emb, float* __restrict__ out, int M) {
    __shared__ u16 As[128 * 32];   // 8 KB
    __shared__ u16 Bs[64 * 32];    // 4 KB
    const int tid = threadIdx.x;
    const int wave = tid >> 6, lane = tid & 63;
    const int q15 = lane & 15, quad = lane >> 4;
    const int rowBase = blockIdx.x * 128;

    floatx4 acc[2][4];
    floatx4 zero = {0.f, 0.f, 0.f, 0.f};
#pragma unroll
    for (int i = 0; i < 2; ++i)
#pragma unroll
        for (int j = 0; j < 4; ++j) acc[i][j] = zero;

    for (int kt = 0; kt < 256; kt += 32) {
#pragma unroll
        for (int rnd = 0; rnd < 2; ++rnd) {
            int slot = rnd * 256 + wave * 64 + lane;
            int r = slot >> 2;
            int c = (slot & 3) * 8;
            int ar = rowBase + r; if (ar >= M) ar = M - 1;
            async16(&As[(rnd * 256 + wave * 64) * 8], &A[(size_t)ar * 256 + kt + c]);
        }
        {
            int slot = wave * 64 + lane;
            int r = slot >> 2;
            int c = (slot & 3) * 8;
            async16(&Bs[(wave * 64) * 8], &Bt[(size_t)r * 256 + kt + c]);
        }
        __syncthreads();

        short8 af[2], bfr[4];
#pragma unroll
        for (int i = 0; i < 2; ++i)
            af[i] = *(const short8*)&As[(wave * 32 + i * 16 + q15) * 32 + quad * 8];
#pragma unroll
        for (int j = 0; j < 4; ++j)
            bfr[j] = *(const short8*)&Bs[(j * 16 + q15) * 32 + quad * 8];
#pragma unroll
        for (int i = 0; i < 2; ++i)
#pragma unroll
            for (int j = 0; j < 4; ++j)
                acc[i][j] = __builtin_amdgcn_mfma_f32_16x16x32_bf16(af[i], bfr[j], acc[i][j], 0, 0, 0);
        __syncthreads();
    }

#pragma unroll
    for (int i = 0; i < 2; ++i) {
#pragma unroll
        for (int rr = 0; rr < 4; ++rr) {
            float v[4];
#pragma unroll
            for (int j = 0; j < 4; ++j) v[j] = acc[i][j][rr] + bias[j * 16 + q15];
            float m = fmaxf(fmaxf(v[0], v[1]), fmaxf(v[2], v[3]));
#pragma unroll
            for (int off = 1; off <= 8; off <<= 1) m = fmaxf(m, __shfl_xor(m, off, 64));
            float s = __expf(v[0] - m) + __expf(v[1] - m) + __expf(v[2] - m) + __expf(v[3] - m);
#pragma unroll
            for (int off = 1; off <= 8; off <<= 1) s += __shfl_xor(s, off, 64);
            float ls = m + logf(s);
            int grow = rowBase + wave * 32 + i * 16 + quad * 4 + rr;
            if (grow < M) {
#pragma unroll
                for (int j = 0; j < 4; ++j) {
                    int col = j * 16 + q15;
                    emb[(size_t)grow * OUTDIM + col] = v[j];
                    out[(size_t)grow * OUTDIM + col] = v[j] - ls;
                }
            }
        }
    }
}

// ---------------- launch ----------------

extern "C" void kernel_launch(void* const* d_in, const int* in_sizes, int n_in,
                              void* d_out, int out_size, void* d_ws, size_t ws_size,
                              hipStream_t stream) {
    const float* x   = (const float*)d_in[0];
    const int*   ei  = (const int*)d_in[1];
    const float* W1  = (const float*)d_in[2];
    const float* at_s1 = (const float*)d_in[3];
    const float* at_d1 = (const float*)d_in[4];
    const float* b1  = (const float*)d_in[5];
    const float* W2  = (const float*)d_in[6];
    const float* at_s2 = (const float*)d_in[7];
    const float* at_d2 = (const float*)d_in[8];
    const float* b2  = (const float*)d_in[9];
    const float* g1  = (const float*)d_in[10];
    const float* be1 = (const float*)d_in[11];
    const float* g2  = (const float*)d_in[12];
    const float* be2 = (const float*)d_in[13];
    const float* Wl  = (const float*)d_in[14];
    const float* bl  = (const float*)d_in[15];

    float* out = (float*)d_out;                        // [N, 64] log_softmax
    float* emb = out + (size_t)NNODES * OUTDIM;        // [N, 64] emb

    char* ws = (char*)d_ws;
    size_t off = 0;
    auto alloc = [&](size_t bytes) {
        void* p = ws + off;
        off += (bytes + 255) & ~(size_t)255;
        return p;
    };
    int*   cnt     = (int*)alloc((size_t)NNODES * 4);
    int*   row_off = (int*)alloc((size_t)(NNODES + 1) * 4);
    int*   nxt     = (int*)alloc((size_t)NNODES * 4);
    int*   bsums   = (int*)alloc(64 * 4);
    int*   csr_src = (int*)alloc((size_t)ETOT * 4);
    int*   csr_dst = (int*)alloc((size_t)ETOT * 4);
    u16*   w4b     = (u16*)alloc((size_t)ETOT * 4 * 2);
    float* asrc    = (float*)alloc((size_t)NNODES * 4 * 4);
    float* adst    = (float*)alloc((size_t)NNODES * 4 * 4);
    u16*   xhp     = (u16*)alloc((size_t)NNODES * HC * 2);   // permuted bf16 table
    u16*   ag_bf   = (u16*)alloc((size_t)NNODES * HC * 2);   // permuted aggregate
    u16*   w1t     = (u16*)alloc((size_t)HC * INDIM * 2);
    u16*   w2t     = (u16*)alloc((size_t)HC * HC * 2);
    u16*   wlt     = (u16*)alloc((size_t)OUTDIM * HC * 2);
    float* part    = (float*)alloc((size_t)NB * 512 * 4);
    float* bias2   = (float*)alloc(HC * 4);
    float* blp     = (float*)alloc(OUTDIM * 4);

    const int scanBlocks = (NNODES + 4095) / 4096;
    const int eBlocks = (ETOT + 255) / 256;

    // ---- CSR build ----
    hipMemsetAsync(cnt, 0, (size_t)NNODES * 4, stream);
    hist_kernel<<<eBlocks, 256, 0, stream>>>(ei, cnt);
    scan1_kernel<<<scanBlocks, 256, 0, stream>>>(cnt, row_off, bsums);
    scan2_kernel<<<scanBlocks, 256, 0, stream>>>(row_off, bsums, nxt);
    fill_csr_kernel<<<eBlocks, 256, 0, stream>>>(ei, nxt, csr_src, csr_dst);

    // ---- weight cast (layer-1 only; layer-2/final fold their own) ----
    wcast_kernel<<<(INDIM * HC + 255) / 256, 256, 0, stream>>>(W1, w1t, INDIM, HC);

    dim3 gemmGrid(2, (NNODES + 127) / 128);

    // ---- Layer 1 (fp32-A gemm + fused alpha + permuted bf16 table) ----
    gemm_gat_kernel<true><<<gemmGrid, 256, 0, stream>>>(x, w1t, nullptr, at_s1, at_d1,
                                                        xhp, asrc, adst, NNODES, INDIM);
    wedge_kernel<<<eBlocks, 256, 0, stream>>>(csr_src, csr_dst, asrc, adst, w4b);
    aggregate_kernel<<<NNODES / 4, 256, 0, stream>>>(row_off, csr_src, w4b, xhp, b1, ag_bf);
    bn_stats_kernel<<<NB, 256, 0, stream>>>(ag_bf, part);
    fold_kernel<<<257, 256, 0, stream>>>(W2, part, g1, be1, nullptr, w2t, bias2, HC);

    // ---- Layer 2 (BN1 folded into W2/bias2; A is permuted, Wt K-permuted to match) ----
    gemm_gat_kernel<false><<<gemmGrid, 256, 0, stream>>>(ag_bf, w2t, bias2, at_s2, at_d2,
                                                         xhp, asrc, adst, NNODES, HC);
    wedge_kernel<<<eBlocks, 256, 0, stream>>>(csr_src, csr_dst, asrc, adst, w4b);
    aggregate_kernel<<<NNODES / 4, 256, 0, stream>>>(row_off, csr_src, w4b, xhp, b2, ag_bf);
    bn_stats_kernel<<<NB, 256, 0, stream>>>(ag_bf, part);
    fold_kernel<<<257, 256, 0, stream>>>(Wl, part, g2, be2, bl, wlt, blp, OUTDIM);

    // ---- Final linear (BN2 folded) + log_softmax, fused ----
    final_ls_kernel<<<(NNODES + 127) / 128, 256, 0, stream>>>(ag_bf, wlt, blp, emb, out, NNODES);
}

// Round 8
// 510.945 us; speedup vs baseline: 1.0063x; 1.0063x over previous
//
#include <hip/hip_runtime.h>
#include <cstdint>

#define NNODES 50000
#define NEDGES 800000
#define ETOT   (NEDGES + NNODES)
#define HEADS 4
#define CH 64
#define HC 256
#define INDIM 256
#define OUTDIM 64
#define NEG_SLOPE 0.2f
#define BN_EPS 1e-5f
#define NB 128   // bn_stats partial blocks

typedef unsigned short u16;
typedef unsigned int u32;
typedef __attribute__((ext_vector_type(8))) short short8;
typedef __attribute__((ext_vector_type(8))) unsigned short ushort8v;
typedef __attribute__((ext_vector_type(4))) float floatx4;

__device__ inline float bf2f(u16 u) {
    union { unsigned int i; float f; } c;
    c.i = ((unsigned int)u) << 16;
    return c.f;
}
__device__ inline u16 f2bf(float f) {
    union { float f; unsigned int i; } c;
    c.f = f;
    unsigned int u = c.i + 0x7fff + ((c.i >> 16) & 1);
    return (u16)(u >> 16);
}
// permuted position of logical channel b (within-head 16x4 transpose)
__device__ __host__ inline int pos256(int b) {
    int h = b >> 6, c = b & 63;
    return h * 64 + (c & 15) * 4 + (c >> 4);
}
__device__ inline void async16(u16* lds, const u16* g) {
    __builtin_amdgcn_global_load_lds(
        (const __attribute__((address_space(1))) unsigned int*)g,
        (__attribute__((address_space(3))) unsigned int*)lds,
        16, 0, 0);
}

// ---------------- CSR build (dst-sorted) ----------------

__global__ void hist_kernel(const int* __restrict__ ei, int* __restrict__ cnt) {
    int t = blockIdx.x * blockDim.x + threadIdx.x;
    if (t >= ETOT) return;
    int d = (t < NEDGES) ? ei[NEDGES + t] : (t - NEDGES);
    atomicAdd(&cnt[d], 1);
}

__global__ void scan1_kernel(const int* __restrict__ cnt, int* __restrict__ row_off,
                             int* __restrict__ blockSums) {
    __shared__ int tsum[256];
    const int tid = threadIdx.x;
    const int base = blockIdx.x * 4096 + tid * 16;
    int local[16];
    int run = 0;
#pragma unroll
    for (int i = 0; i < 16; ++i) {
        int idx = base + i;
        int v = (idx < NNODES) ? cnt[idx] : 0;
        local[i] = run;
        run += v;
    }
    tsum[tid] = run;
    __syncthreads();
    for (int d = 1; d < 256; d <<= 1) {
        int v = (tid >= d) ? tsum[tid - d] : 0;
        __syncthreads();
        tsum[tid] += v;
        __syncthreads();
    }
    int excl = (tid == 0) ? 0 : tsum[tid - 1];
#pragma unroll
    for (int i = 0; i < 16; ++i) {
        int idx = base + i;
        if (idx < NNODES) row_off[idx] = excl + local[i];
    }
    if (tid == 0) blockSums[blockIdx.x] = tsum[255];
}

__global__ void scan2_kernel(int* __restrict__ row_off, const int* __restrict__ blockSums,
                             int* __restrict__ nxt) {
    __shared__ int sprefix;
    if (threadIdx.x == 0) {
        int p = 0;
        for (int b = 0; b < (int)blockIdx.x; ++b) p += blockSums[b];
        sprefix = p;
    }
    __syncthreads();
    int prefix = sprefix;
    int base = blockIdx.x * 4096 + threadIdx.x * 16;
#pragma unroll
    for (int i = 0; i < 16; ++i) {
        int idx = base + i;
        if (idx < NNODES) {
            int v = row_off[idx] + prefix;
            row_off[idx] = v;
            nxt[idx] = v;
        }
    }
    if (blockIdx.x == 0 && threadIdx.x == 0) row_off[NNODES] = ETOT;
}

// one 8B store per edge (one dirty line instead of two)
__global__ void fill_csr_kernel(const int* __restrict__ ei, int* __restrict__ nxt,
                                int2* __restrict__ csr_pair) {
    int t = blockIdx.x * blockDim.x + threadIdx.x;
    if (t >= ETOT) return;
    int s, d;
    if (t < NEDGES) { s = ei[t]; d = ei[NEDGES + t]; }
    else            { s = d = t - NEDGES; }
    int pos = atomicAdd(&nxt[d], 1);
    csr_pair[pos] = make_int2(s, d);
}

// ---------------- weight cast: W [K][Ncols] fp32 -> Wt [Ncols][K] bf16 ----------------

__global__ void wcast_kernel(const float* __restrict__ W, u16* __restrict__ Wt,
                             int K, int Ncols) {
    int t = blockIdx.x * blockDim.x + threadIdx.x;
    if (t >= K * Ncols) return;
    int k = t / Ncols, n = t - k * Ncols;
    Wt[n * K + k] = f2bf(W[t]);
}

// ---------------- bf16 MFMA GEMM + fused alpha + permuted bf16 output ----------------

template <bool AF32>
__global__ __launch_bounds__(256)
void gemm_gat_kernel(const void* __restrict__ Ap, const u16* __restrict__ Bt,
                     const float* __restrict__ bias,
                     const float* __restrict__ att_s, const float* __restrict__ att_d,
                     u16* __restrict__ xhp, float* __restrict__ asrc,
                     float* __restrict__ adst, int M, int K) {
    __shared__ u16 As[128 * 32];
    __shared__ u16 Bs[128 * 32];
    const int tid = threadIdx.x;
    const int wave = tid >> 6, lane = tid & 63;
    const int q15 = lane & 15, quad = lane >> 4;
    const int rowBase = blockIdx.y * 128;
    const int colBase = blockIdx.x * 128;
    const int waveM = (wave >> 1) * 64, waveN = (wave & 1) * 64;
    const int head = blockIdx.x * 2 + (wave & 1);

    floatx4 acc[4][4];
    floatx4 zero = {0.f, 0.f, 0.f, 0.f};
#pragma unroll
    for (int i = 0; i < 4; ++i)
#pragma unroll
        for (int j = 0; j < 4; ++j) acc[i][j] = zero;

    for (int kt = 0; kt < K; kt += 32) {
        if constexpr (AF32) {
            const float* A32 = (const float*)Ap;
#pragma unroll
            for (int rnd = 0; rnd < 4; ++rnd) {
                int slot = rnd * 256 + tid;
                int r = slot >> 3, c4 = (slot & 7) * 4;
                int ar = rowBase + r; if (ar >= M) ar = M - 1;
                float4 fv = *(const float4*)&A32[(size_t)ar * K + kt + c4];
                ushort4 o;
                o.x = f2bf(fv.x); o.y = f2bf(fv.y); o.z = f2bf(fv.z); o.w = f2bf(fv.w);
                *(ushort4*)&As[r * 32 + c4] = o;
            }
#pragma unroll
            for (int q = 0; q < 2; ++q) {
                int e8 = (wave * 2 + q) * 64 + lane;
                int r = e8 >> 2, c = (e8 & 3) * 8;
                async16(&Bs[(wave * 2 + q) * 512], &Bt[(size_t)(colBase + r) * K + kt + c]);
            }
        } else {
            const u16* A16 = (const u16*)Ap;
#pragma unroll
            for (int q = 0; q < 2; ++q) {
                int e8 = (wave * 2 + q) * 64 + lane;
                int r = e8 >> 2, c = (e8 & 3) * 8;
                int ar = rowBase + r; if (ar >= M) ar = M - 1;
                async16(&As[(wave * 2 + q) * 512], &A16[(size_t)ar * K + kt + c]);
                async16(&Bs[(wave * 2 + q) * 512], &Bt[(size_t)(colBase + r) * K + kt + c]);
            }
        }
        __syncthreads();

        short8 af[4], bfr[4];
#pragma unroll
        for (int i = 0; i < 4; ++i)
            af[i] = *(const short8*)&As[(waveM + i * 16 + q15) * 32 + quad * 8];
#pragma unroll
        for (int j = 0; j < 4; ++j)
            bfr[j] = *(const short8*)&Bs[(waveN + j * 16 + q15) * 32 + quad * 8];
#pragma unroll
        for (int i = 0; i < 4; ++i)
#pragma unroll
            for (int j = 0; j < 4; ++j)
                acc[i][j] = __builtin_amdgcn_mfma_f32_16x16x32_bf16(af[i], bfr[j], acc[i][j], 0, 0, 0);
        __syncthreads();
    }

    float bv[4], atsv[4], atdv[4];
#pragma unroll
    for (int j = 0; j < 4; ++j) {
        int gcol = colBase + waveN + j * 16 + q15;
        bv[j] = bias ? bias[gcol] : 0.f;
        int hc = head * CH + j * 16 + q15;
        atsv[j] = att_s[hc];
        atdv[j] = att_d[hc];
    }
    const int pbase = head * 64 + q15 * 4;

#pragma unroll
    for (int i = 0; i < 4; ++i) {
#pragma unroll
        for (int rr = 0; rr < 4; ++rr) {
            int grow = rowBase + waveM + i * 16 + quad * 4 + rr;
            float v[4];
#pragma unroll
            for (int j = 0; j < 4; ++j) v[j] = acc[i][j][rr] + bv[j];
            float s = v[0] * atsv[0] + v[1] * atsv[1] + v[2] * atsv[2] + v[3] * atsv[3];
            float d = v[0] * atdv[0] + v[1] * atdv[1] + v[2] * atdv[2] + v[3] * atdv[3];
#pragma unroll
            for (int off = 1; off <= 8; off <<= 1) {
                s += __shfl_xor(s, off, 64);
                d += __shfl_xor(d, off, 64);
            }
            ushort4 o;
            o.x = f2bf(v[0]); o.y = f2bf(v[1]); o.z = f2bf(v[2]); o.w = f2bf(v[3]);
            if (grow < M) {
                *(ushort4*)&xhp[(size_t)grow * HC + pbase] = o;
                if (q15 == 0) {
                    asrc[grow * 4 + head] = s;
                    adst[grow * 4 + head] = d;
                }
            }
        }
    }
}

// ---------------- per-edge softmax weights (unnormalized, bf16): w4b[e][h] ----------------

__global__ void wedge_kernel(const int2* __restrict__ csr_pair,
                             const float* __restrict__ asrc, const float* __restrict__ adst,
                             u16* __restrict__ w4b) {
    int e = blockIdx.x * blockDim.x + threadIdx.x;
    if (e >= ETOT) return;
    int2 pr = csr_pair[e];
    float4 a = *(const float4*)&asrc[pr.x * 4];
    float4 b = *(const float4*)&adst[pr.y * 4];
    ushort4 r;
    float v;
    v = a.x + b.x; v = v > 0.f ? v : NEG_SLOPE * v; r.x = f2bf(__expf(v));
    v = a.y + b.y; v = v > 0.f ? v : NEG_SLOPE * v; r.y = f2bf(__expf(v));
    v = a.z + b.z; v = v > 0.f ? v : NEG_SLOPE * v; r.z = f2bf(__expf(v));
    v = a.w + b.w; v = v > 0.f ? v : NEG_SLOPE * v; r.w = f2bf(__expf(v));
    *(ushort4*)&w4b[(size_t)e * 4] = r;
}

// ---------------- fused aggregate over permuted bf16 table ----------------
// 1 wave = 1 dst node. Edge indices + weights register-staged by one coalesced
// 64-wide load, then broadcast via v_readlane (no load->gather dependency chain).

__global__ __launch_bounds__(256)
void aggregate_kernel(const int* __restrict__ row_off, const int2* __restrict__ csr_pair,
                      const u16* __restrict__ w4b, const u16* __restrict__ xhp,
                      const float* __restrict__ bias, u16* __restrict__ out) {
    const int g = threadIdx.x >> 6;
    const int lane = threadIdx.x & 63;
    const int d = blockIdx.x * 4 + g;
    const int h = lane >> 4;
    const int c16 = lane & 15;
    const int poff = h * 64 + c16 * 4;
    const int hsel = h & 2;              // pick .y word if h>=2
    const int hsh = (h & 1) * 16;        // shift within word
    const int start = row_off[d], end = row_off[d + 1];
    float a0 = 0.f, a1 = 0.f, a2 = 0.f, a3 = 0.f, den = 0.f;

    for (int base = start; base < end; base += 64) {
        const int cnt = min(64, end - base);
        int sv = 0;
        u32 wx = 0, wy = 0;
        if (lane < cnt) {
            int e = base + lane;
            sv = csr_pair[e].x;
            uint2 wq = *(const uint2*)&w4b[(size_t)e * 4];
            wx = wq.x; wy = wq.y;
        }
        int k = 0;
        for (; k + 3 < cnt; k += 4) {
            int s0 = __builtin_amdgcn_readlane(sv, k);
            int s1 = __builtin_amdgcn_readlane(sv, k + 1);
            int s2 = __builtin_amdgcn_readlane(sv, k + 2);
            int s3 = __builtin_amdgcn_readlane(sv, k + 3);
            u32 x0w = __builtin_amdgcn_readlane((int)wx, k), y0w = __builtin_amdgcn_readlane((int)wy, k);
            u32 x1w = __builtin_amdgcn_readlane((int)wx, k + 1), y1w = __builtin_amdgcn_readlane((int)wy, k + 1);
            u32 x2w = __builtin_amdgcn_readlane((int)wx, k + 2), y2w = __builtin_amdgcn_readlane((int)wy, k + 2);
            u32 x3w = __builtin_amdgcn_readlane((int)wx, k + 3), y3w = __builtin_amdgcn_readlane((int)wy, k + 3);
            ushort4 v0 = *(const ushort4*)&xhp[(size_t)s0 * HC + poff];
            ushort4 v1 = *(const ushort4*)&xhp[(size_t)s1 * HC + poff];
            ushort4 v2 = *(const ushort4*)&xhp[(size_t)s2 * HC + poff];
            ushort4 v3 = *(const ushort4*)&xhp[(size_t)s3 * HC + poff];
            float w0 = bf2f((u16)((hsel ? y0w : x0w) >> hsh));
            float w1 = bf2f((u16)((hsel ? y1w : x1w) >> hsh));
            float w2 = bf2f((u16)((hsel ? y2w : x2w) >> hsh));
            float w3 = bf2f((u16)((hsel ? y3w : x3w) >> hsh));
            den += (w0 + w1) + (w2 + w3);
            a0 += w0 * bf2f(v0.x) + w1 * bf2f(v1.x) + w2 * bf2f(v2.x) + w3 * bf2f(v3.x);
            a1 += w0 * bf2f(v0.y) + w1 * bf2f(v1.y) + w2 * bf2f(v2.y) + w3 * bf2f(v3.y);
            a2 += w0 * bf2f(v0.z) + w1 * bf2f(v1.z) + w2 * bf2f(v2.z) + w3 * bf2f(v3.z);
            a3 += w0 * bf2f(v0.w) + w1 * bf2f(v1.w) + w2 * bf2f(v2.w) + w3 * bf2f(v3.w);
        }
        for (; k < cnt; ++k) {
            int s0 = __builtin_amdgcn_readlane(sv, k);
            u32 x0w = __builtin_amdgcn_readlane((int)wx, k), y0w = __builtin_amdgcn_readlane((int)wy, k);
            ushort4 v0 = *(const ushort4*)&xhp[(size_t)s0 * HC + poff];
            float w0 = bf2f((u16)((hsel ? y0w : x0w) >> hsh));
            den += w0;
            a0 += w0 * bf2f(v0.x);
            a1 += w0 * bf2f(v0.y);
            a2 += w0 * bf2f(v0.z);
            a3 += w0 * bf2f(v0.w);
        }
    }
    float inv = 1.f / (den + 1e-16f);
    const int ch0 = h * 64 + c16;
    ushort4 o;
    o.x = f2bf(a0 * inv + bias[ch0 +  0]);
    o.y = f2bf(a1 * inv + bias[ch0 + 16]);
    o.z = f2bf(a2 * inv + bias[ch0 + 32]);
    o.w = f2bf(a3 * inv + bias[ch0 + 48]);
    *(ushort4*)&out[(size_t)d * HC + poff] = o;   // permuted, coalesced
}

// ---------------- BatchNorm stats over permuted buffer (positional) ----------------

__global__ __launch_bounds__(256)
void bn_stats_kernel(const u16* __restrict__ x, float* __restrict__ part) {
    const int tid = threadIdx.x;
    float s[8] = {}, s2[8] = {};
    const size_t total = (size_t)NNODES * HC;
    const size_t stride = (size_t)NB * 256 * 8;
    for (size_t f = ((size_t)blockIdx.x * 256 + tid) * 8; f < total; f += stride) {
        ushort8v v = *(const ushort8v*)&x[f];
#pragma unroll
        for (int i = 0; i < 8; ++i) {
            float t = bf2f(v[i]);
            s[i] += t;
            s2[i] += t * t;
        }
    }
#pragma unroll
    for (int i = 0; i < 8; ++i) {
        s[i] += __shfl_xor(s[i], 32, 64);
        s2[i] += __shfl_xor(s2[i], 32, 64);
    }
    __shared__ float red[4][512];
    const int wave = tid >> 6, lane = tid & 63;
    if (lane < 32) {
#pragma unroll
        for (int i = 0; i < 8; ++i) {
            red[wave][lane * 8 + i] = s[i];
            red[wave][256 + lane * 8 + i] = s2[i];
        }
    }
    __syncthreads();
    for (int j = tid; j < 512; j += 256)
        part[(size_t)blockIdx.x * 512 + j] = red[0][j] + red[1][j] + red[2][j] + red[3][j];
}

// ---------------- BN fold (permutation-aware) ----------------

__global__ __launch_bounds__(256)
void fold_kernel(const float* __restrict__ W, const float* __restrict__ part,
                 const float* __restrict__ g, const float* __restrict__ beta,
                 const float* __restrict__ baseBias,
                 u16* __restrict__ Wt, float* __restrict__ biasOut, int Ncols) {
    __shared__ float sh[256];
    __shared__ float stat2[2];
    const int b = blockIdx.x;
    const int tid = threadIdx.x;
    if (b < 256) {
        const int p = pos256(b);
        const int wave = tid >> 6, lane = tid & 63;
        if (wave < 2) {
            int off = wave * 256;
            float v = part[(size_t)lane * 512 + off + p] + part[(size_t)(lane + 64) * 512 + off + p];
#pragma unroll
            for (int o = 1; o <= 32; o <<= 1) v += __shfl_xor(v, o, 64);
            if (lane == 0) stat2[wave] = v;
        }
        __syncthreads();
        float mu = stat2[0] * (1.f / NNODES);
        float var = stat2[1] * (1.f / NNODES) - mu * mu;
        float rg = rsqrtf(var + BN_EPS) * g[b];
        for (int n = tid; n < Ncols; n += 256)
            Wt[n * 256 + p] = f2bf(W[b * Ncols + n] * rg);
    } else {
        const int p = pos256(tid);
        float sum = 0.f, sq = 0.f;
        for (int k = 0; k < NB; ++k) {
            sum += part[(size_t)k * 512 + p];
            sq += part[(size_t)k * 512 + 256 + p];
        }
        float mu = sum * (1.f / NNODES);
        float var = sq * (1.f / NNODES) - mu * mu;
        float rg = rsqrtf(var + BN_EPS) * g[tid];
        sh[tid] = beta[tid] - mu * rg;
        __syncthreads();
        if (tid < Ncols) {
            float acc = baseBias ? baseBias[tid] : 0.f;
            for (int k = 0; k < 256; ++k) acc += sh[k] * W[k * Ncols + tid];
            biasOut[tid] = acc;
        }
    }
}

// ---------------- fused final GEMM (M x 64, K=256) + bias + log_softmax ----------------

__global__ __launch_bounds__(256)
void final_ls_kernel(const u16* __restrict__ A, const u16* __restrict__ Bt,
                     const float* __restrict__ bias,
                     float* __restrict__ emb, float* __restrict__ out, int M) {
    __shared__ u16 As[128 * 32];
    __shared__ u16 Bs[64 * 32];
    const int tid = threadIdx.x;
    const int wave = tid >> 6, lane = tid & 63;
    const int q15 = lane & 15, quad = lane >> 4;
    const int rowBase = blockIdx.x * 128;

    floatx4 acc[2][4];
    floatx4 zero = {0.f, 0.f, 0.f, 0.f};
#pragma unroll
    for (int i = 0; i < 2; ++i)
#pragma unroll
        for (int j = 0; j < 4; ++j) acc[i][j] = zero;

    for (int kt = 0; kt < 256; kt += 32) {
#pragma unroll
        for (int rnd = 0; rnd < 2; ++rnd) {
            int slot = rnd * 256 + wave * 64 + lane;
            int r = slot >> 2;
            int c = (slot & 3) * 8;
            int ar = rowBase + r; if (ar >= M) ar = M - 1;
            async16(&As[(rnd * 256 + wave * 64) * 8], &A[(size_t)ar * 256 + kt + c]);
        }
        {
            int slot = wave * 64 + lane;
            int r = slot >> 2;
            int c = (slot & 3) * 8;
            async16(&Bs[(wave * 64) * 8], &Bt[(size_t)r * 256 + kt + c]);
        }
        __syncthreads();

        short8 af[2], bfr[4];
#pragma unroll
        for (int i = 0; i < 2; ++i)
            af[i] = *(const short8*)&As[(wave * 32 + i * 16 + q15) * 32 + quad * 8];
#pragma unroll
        for (int j = 0; j < 4; ++j)
            bfr[j] = *(const short8*)&Bs[(j * 16 + q15) * 32 + quad * 8];
#pragma unroll
        for (int i = 0; i < 2; ++i)
#pragma unroll
            for (int j = 0; j < 4; ++j)
                acc[i][j] = __builtin_amdgcn_mfma_f32_16x16x32_bf16(af[i], bfr[j], acc[i][j], 0, 0, 0);
        __syncthreads();
    }

#pragma unroll
    for (int i = 0; i < 2; ++i) {
#pragma unroll
        for (int rr = 0; rr < 4; ++rr) {
            float v[4];
#pragma unroll
            for (int j = 0; j < 4; ++j) v[j] = acc[i][j][rr] + bias[j * 16 + q15];
            float m = fmaxf(fmaxf(v[0], v[1]), fmaxf(v[2], v[3]));
#pragma unroll
            for (int off = 1; off <= 8; off <<= 1) m = fmaxf(m, __shfl_xor(m, off, 64));
            float s = __expf(v[0] - m) + __expf(v[1] - m) + __expf(v[2] - m) + __expf(v[3] - m);
#pragma unroll
            for (int off = 1; off <= 8; off <<= 1) s += __shfl_xor(s, off, 64);
            float ls = m + logf(s);
            int grow = rowBase + wave * 32 + i * 16 + quad * 4 + rr;
            if (grow < M) {
#pragma unroll
                for (int j = 0; j < 4; ++j) {
                    int col = j * 16 + q15;
                    emb[(size_t)grow * OUTDIM + col] = v[j];
                    out[(size_t)grow * OUTDIM + col] = v[j] - ls;
                }
            }
        }
    }
}

// ---------------- launch ----------------

extern "C" void kernel_launch(void* const* d_in, const int* in_sizes, int n_in,
                              void* d_out, int out_size, void* d_ws, size_t ws_size,
                              hipStream_t stream) {
    const float* x   = (const float*)d_in[0];
    const int*   ei  = (const int*)d_in[1];
    const float* W1  = (const float*)d_in[2];
    const float* at_s1 = (const float*)d_in[3];
    const float* at_d1 = (const float*)d_in[4];
    const float* b1  = (const float*)d_in[5];
    const float* W2  = (const float*)d_in[6];
    const float* at_s2 = (const float*)d_in[7];
    const float* at_d2 = (const float*)d_in[8];
    const float* b2  = (const float*)d_in[9];
    const float* g1  = (const float*)d_in[10];
    const float* be1 = (const float*)d_in[11];
    const float* g2  = (const float*)d_in[12];
    const float* be2 = (const float*)d_in[13];
    const float* Wl  = (const float*)d_in[14];
    const float* bl  = (const float*)d_in[15];

    float* out = (float*)d_out;                        // [N, 64] log_softmax
    float* emb = out + (size_t)NNODES * OUTDIM;        // [N, 64] emb

    char* ws = (char*)d_ws;
    size_t off = 0;
    auto alloc = [&](size_t bytes) {
        void* p = ws + off;
        off += (bytes + 255) & ~(size_t)255;
        return p;
    };
    int*   cnt     = (int*)alloc((size_t)NNODES * 4);
    int*   row_off = (int*)alloc((size_t)(NNODES + 1) * 4);
    int*   nxt     = (int*)alloc((size_t)NNODES * 4);
    int*   bsums   = (int*)alloc(64 * 4);
    int2*  csr_pair= (int2*)alloc((size_t)ETOT * 8);
    u16*   w4b     = (u16*)alloc((size_t)ETOT * 4 * 2);
    float* asrc    = (float*)alloc((size_t)NNODES * 4 * 4);
    float* adst    = (float*)alloc((size_t)NNODES * 4 * 4);
    u16*   xhp     = (u16*)alloc((size_t)NNODES * HC * 2);   // permuted bf16 table
    u16*   ag_bf   = (u16*)alloc((size_t)NNODES * HC * 2);   // permuted aggregate
    u16*   w1t     = (u16*)alloc((size_t)HC * INDIM * 2);
    u16*   w2t     = (u16*)alloc((size_t)HC * HC * 2);
    u16*   wlt     = (u16*)alloc((size_t)OUTDIM * HC * 2);
    float* part    = (float*)alloc((size_t)NB * 512 * 4);
    float* bias2   = (float*)alloc(HC * 4);
    float* blp     = (float*)alloc(OUTDIM * 4);

    const int scanBlocks = (NNODES + 4095) / 4096;
    const int eBlocks = (ETOT + 255) / 256;

    // ---- CSR build ----
    hipMemsetAsync(cnt, 0, (size_t)NNODES * 4, stream);
    hist_kernel<<<eBlocks, 256, 0, stream>>>(ei, cnt);
    scan1_kernel<<<scanBlocks, 256, 0, stream>>>(cnt, row_off, bsums);
    scan2_kernel<<<scanBlocks, 256, 0, stream>>>(row_off, bsums, nxt);
    fill_csr_kernel<<<eBlocks, 256, 0, stream>>>(ei, nxt, csr_pair);

    // ---- weight cast (layer-1 only; layer-2/final fold their own) ----
    wcast_kernel<<<(INDIM * HC + 255) / 256, 256, 0, stream>>>(W1, w1t, INDIM, HC);

    dim3 gemmGrid(2, (NNODES + 127) / 128);

    // ---- Layer 1 (fp32-A gemm + fused alpha + permuted bf16 table) ----
    gemm_gat_kernel<true><<<gemmGrid, 256, 0, stream>>>(x, w1t, nullptr, at_s1, at_d1,
                                                        xhp, asrc, adst, NNODES, INDIM);
    wedge_kernel<<<eBlocks, 256, 0, stream>>>(csr_pair, asrc, adst, w4b);
    aggregate_kernel<<<NNODES / 4, 256, 0, stream>>>(row_off, csr_pair, w4b, xhp, b1, ag_bf);
    bn_stats_kernel<<<NB, 256, 0, stream>>>(ag_bf, part);
    fold_kernel<<<257, 256, 0, stream>>>(W2, part, g1, be1, nullptr, w2t, bias2, HC);

    // ---- Layer 2 (BN1 folded into W2/bias2; A permuted, Wt K-permuted to match) ----
    gemm_gat_kernel<false><<<gemmGrid, 256, 0, stream>>>(ag_bf, w2t, bias2, at_s2, at_d2,
                                                         xhp, asrc, adst, NNODES, HC);
    wedge_kernel<<<eBlocks, 256, 0, stream>>>(csr_pair, asrc, adst, w4b);
    aggregate_kernel<<<NNODES / 4, 256, 0, stream>>>(row_off, csr_pair, w4b, xhp, b2, ag_bf);
    bn_stats_kernel<<<NB, 256, 0, stream>>>(ag_bf, part);
    fold_kernel<<<257, 256, 0, stream>>>(Wl, part, g2, be2, bl, wlt, blp, OUTDIM);

    // ---- Final linear (BN2 folded) + log_softmax, fused ----
    final_ls_kernel<<<(NNODES + 127) / 128, 256, 0, stream>>>(ag_bf, wlt, blp, emb, out, NNODES);
}

// Round 9
// 492.830 us; speedup vs baseline: 1.0433x; 1.0368x over previous
//
#include <hip/hip_runtime.h>
#include <cstdint>

#define NNODES 50000
#define NEDGES 800000
#define ETOT   (NEDGES + NNODES)
#define HEADS 4
#define CH 64
#define HC 256
#define INDIM 256
#define OUTDIM 64
#define NEG_SLOPE 0.2f
#define BN_EPS 1e-5f
#define NB 128   // bn_stats partial blocks

typedef unsigned short u16;
typedef unsigned int u32;
typedef __attribute__((ext_vector_type(8))) short short8;
typedef __attribute__((ext_vector_type(8))) unsigned short ushort8v;
typedef __attribute__((ext_vector_type(4))) float floatx4;

__device__ inline float bf2f(u16 u) {
    union { unsigned int i; float f; } c;
    c.i = ((unsigned int)u) << 16;
    return c.f;
}
__device__ inline u16 f2bf(float f) {
    union { float f; unsigned int i; } c;
    c.f = f;
    unsigned int u = c.i + 0x7fff + ((c.i >> 16) & 1);
    return (u16)(u >> 16);
}
// permuted position of logical channel b (within-head 16x4 transpose)
__device__ __host__ inline int pos256(int b) {
    int h = b >> 6, c = b & 63;
    return h * 64 + (c & 15) * 4 + (c >> 4);
}
__device__ inline void async16(u16* lds, const u16* g) {
    __builtin_amdgcn_global_load_lds(
        (const __attribute__((address_space(1))) unsigned int*)g,
        (__attribute__((address_space(3))) unsigned int*)lds,
        16, 0, 0);
}

// ---------------- CSR build (dst-sorted) ----------------

__global__ void hist_kernel(const int* __restrict__ ei, int* __restrict__ cnt) {
    int t = blockIdx.x * blockDim.x + threadIdx.x;
    if (t >= ETOT) return;
    int d = (t < NEDGES) ? ei[NEDGES + t] : (t - NEDGES);
    atomicAdd(&cnt[d], 1);
}

__global__ void scan1_kernel(const int* __restrict__ cnt, int* __restrict__ row_off,
                             int* __restrict__ blockSums) {
    __shared__ int tsum[256];
    const int tid = threadIdx.x;
    const int base = blockIdx.x * 4096 + tid * 16;
    int local[16];
    int run = 0;
#pragma unroll
    for (int i = 0; i < 16; ++i) {
        int idx = base + i;
        int v = (idx < NNODES) ? cnt[idx] : 0;
        local[i] = run;
        run += v;
    }
    tsum[tid] = run;
    __syncthreads();
    for (int d = 1; d < 256; d <<= 1) {
        int v = (tid >= d) ? tsum[tid - d] : 0;
        __syncthreads();
        tsum[tid] += v;
        __syncthreads();
    }
    int excl = (tid == 0) ? 0 : tsum[tid - 1];
#pragma unroll
    for (int i = 0; i < 16; ++i) {
        int idx = base + i;
        if (idx < NNODES) row_off[idx] = excl + local[i];
    }
    if (tid == 0) blockSums[blockIdx.x] = tsum[255];
}

__global__ void scan2_kernel(int* __restrict__ row_off, const int* __restrict__ blockSums,
                             int* __restrict__ nxt) {
    __shared__ int sprefix;
    if (threadIdx.x == 0) {
        int p = 0;
        for (int b = 0; b < (int)blockIdx.x; ++b) p += blockSums[b];
        sprefix = p;
    }
    __syncthreads();
    int prefix = sprefix;
    int base = blockIdx.x * 4096 + threadIdx.x * 16;
#pragma unroll
    for (int i = 0; i < 16; ++i) {
        int idx = base + i;
        if (idx < NNODES) {
            int v = row_off[idx] + prefix;
            row_off[idx] = v;
            nxt[idx] = v;
        }
    }
    if (blockIdx.x == 0 && threadIdx.x == 0) row_off[NNODES] = ETOT;
}

// 4 edges per thread (independent atomic->store chains for MLP), 4B payload.
#define FILL_S (ETOT / 4)   // 212500, exact
__global__ void fill_csr_kernel(const int* __restrict__ ei, int* __restrict__ nxt,
                                int* __restrict__ csr_src) {
    int t = blockIdx.x * blockDim.x + threadIdx.x;
    if (t >= FILL_S) return;
    int s[4], d[4], p[4];
#pragma unroll
    for (int k = 0; k < 4; ++k) {
        int e = t + k * FILL_S;
        if (e < NEDGES) { s[k] = ei[e]; d[k] = ei[NEDGES + e]; }
        else            { s[k] = d[k] = e - NEDGES; }
    }
#pragma unroll
    for (int k = 0; k < 4; ++k) p[k] = atomicAdd(&nxt[d[k]], 1);
#pragma unroll
    for (int k = 0; k < 4; ++k) csr_src[p[k]] = s[k];
}

// ---------------- weight cast: W [K][Ncols] fp32 -> Wt [Ncols][K] bf16 ----------------

__global__ void wcast_kernel(const float* __restrict__ W, u16* __restrict__ Wt,
                             int K, int Ncols) {
    int t = blockIdx.x * blockDim.x + threadIdx.x;
    if (t >= K * Ncols) return;
    int k = t / Ncols, n = t - k * Ncols;
    Wt[n * K + k] = f2bf(W[t]);
}

// ---------------- bf16 MFMA GEMM + fused alpha + permuted bf16 output ----------------

template <bool AF32>
__global__ __launch_bounds__(256)
void gemm_gat_kernel(const void* __restrict__ Ap, const u16* __restrict__ Bt,
                     const float* __restrict__ bias,
                     const float* __restrict__ att_s, const float* __restrict__ att_d,
                     u16* __restrict__ xhp, float* __restrict__ asrc,
                     float* __restrict__ adst, int M, int K) {
    __shared__ u16 As[128 * 32];
    __shared__ u16 Bs[128 * 32];
    const int tid = threadIdx.x;
    const int wave = tid >> 6, lane = tid & 63;
    const int q15 = lane & 15, quad = lane >> 4;
    const int rowBase = blockIdx.y * 128;
    const int colBase = blockIdx.x * 128;
    const int waveM = (wave >> 1) * 64, waveN = (wave & 1) * 64;
    const int head = blockIdx.x * 2 + (wave & 1);

    floatx4 acc[4][4];
    floatx4 zero = {0.f, 0.f, 0.f, 0.f};
#pragma unroll
    for (int i = 0; i < 4; ++i)
#pragma unroll
        for (int j = 0; j < 4; ++j) acc[i][j] = zero;

    for (int kt = 0; kt < K; kt += 32) {
        if constexpr (AF32) {
            const float* A32 = (const float*)Ap;
#pragma unroll
            for (int rnd = 0; rnd < 4; ++rnd) {
                int slot = rnd * 256 + tid;
                int r = slot >> 3, c4 = (slot & 7) * 4;
                int ar = rowBase + r; if (ar >= M) ar = M - 1;
                float4 fv = *(const float4*)&A32[(size_t)ar * K + kt + c4];
                ushort4 o;
                o.x = f2bf(fv.x); o.y = f2bf(fv.y); o.z = f2bf(fv.z); o.w = f2bf(fv.w);
                *(ushort4*)&As[r * 32 + c4] = o;
            }
#pragma unroll
            for (int q = 0; q < 2; ++q) {
                int e8 = (wave * 2 + q) * 64 + lane;
                int r = e8 >> 2, c = (e8 & 3) * 8;
                async16(&Bs[(wave * 2 + q) * 512], &Bt[(size_t)(colBase + r) * K + kt + c]);
            }
        } else {
            const u16* A16 = (const u16*)Ap;
#pragma unroll
            for (int q = 0; q < 2; ++q) {
                int e8 = (wave * 2 + q) * 64 + lane;
                int r = e8 >> 2, c = (e8 & 3) * 8;
                int ar = rowBase + r; if (ar >= M) ar = M - 1;
                async16(&As[(wave * 2 + q) * 512], &A16[(size_t)ar * K + kt + c]);
                async16(&Bs[(wave * 2 + q) * 512], &Bt[(size_t)(colBase + r) * K + kt + c]);
            }
        }
        __syncthreads();

        short8 af[4], bfr[4];
#pragma unroll
        for (int i = 0; i < 4; ++i)
            af[i] = *(const short8*)&As[(waveM + i * 16 + q15) * 32 + quad * 8];
#pragma unroll
        for (int j = 0; j < 4; ++j)
            bfr[j] = *(const short8*)&Bs[(waveN + j * 16 + q15) * 32 + quad * 8];
#pragma unroll
        for (int i = 0; i < 4; ++i)
#pragma unroll
            for (int j = 0; j < 4; ++j)
                acc[i][j] = __builtin_amdgcn_mfma_f32_16x16x32_bf16(af[i], bfr[j], acc[i][j], 0, 0, 0);
        __syncthreads();
    }

    float bv[4], atsv[4], atdv[4];
#pragma unroll
    for (int j = 0; j < 4; ++j) {
        int gcol = colBase + waveN + j * 16 + q15;
        bv[j] = bias ? bias[gcol] : 0.f;
        int hc = head * CH + j * 16 + q15;
        atsv[j] = att_s[hc];
        atdv[j] = att_d[hc];
    }
    const int pbase = head * 64 + q15 * 4;

#pragma unroll
    for (int i = 0; i < 4; ++i) {
#pragma unroll
        for (int rr = 0; rr < 4; ++rr) {
            int grow = rowBase + waveM + i * 16 + quad * 4 + rr;
            float v[4];
#pragma unroll
            for (int j = 0; j < 4; ++j) v[j] = acc[i][j][rr] + bv[j];
            float s = v[0] * atsv[0] + v[1] * atsv[1] + v[2] * atsv[2] + v[3] * atsv[3];
            float d = v[0] * atdv[0] + v[1] * atdv[1] + v[2] * atdv[2] + v[3] * atdv[3];
#pragma unroll
            for (int off = 1; off <= 8; off <<= 1) {
                s += __shfl_xor(s, off, 64);
                d += __shfl_xor(d, off, 64);
            }
            ushort4 o;
            o.x = f2bf(v[0]); o.y = f2bf(v[1]); o.z = f2bf(v[2]); o.w = f2bf(v[3]);
            if (grow < M) {
                *(ushort4*)&xhp[(size_t)grow * HC + pbase] = o;
                if (q15 == 0) {
                    asrc[grow * 4 + head] = s;
                    adst[grow * 4 + head] = d;
                }
            }
        }
    }
}

// ---------------- fused softmax+aggregate over permuted bf16 table ----------------
// 1 wave = 1 dst node. Batch of 64 edges: each lane loads its edge's src (coalesced)
// and gathers asrc[src] (float4) to compute all 4 head weights in parallel
// (adst[d] is wave-uniform), packed as bf16 pairs in wx/wy. Serial loop broadcasts
// indices+weights via v_readlane -> 4 back-to-back random row gathers.

__global__ __launch_bounds__(256)
void aggregate_kernel(const int* __restrict__ row_off, const int* __restrict__ csr_src,
                      const float* __restrict__ asrc, const float* __restrict__ adst,
                      const u16* __restrict__ xhp, const float* __restrict__ bias,
                      u16* __restrict__ out) {
    const int g = threadIdx.x >> 6;
    const int lane = threadIdx.x & 63;
    const int d = blockIdx.x * 4 + g;
    const int h = lane >> 4;
    const int c16 = lane & 15;
    const int poff = h * 64 + c16 * 4;
    const int hsel = h & 2;              // pick wy if h>=2
    const int hsh = (h & 1) * 16;        // shift within word
    const int start = row_off[d], end = row_off[d + 1];
    const float4 ad4 = *(const float4*)&adst[d * 4];   // wave-uniform
    float a0 = 0.f, a1 = 0.f, a2 = 0.f, a3 = 0.f, den = 0.f;

    for (int base = start; base < end; base += 64) {
        const int cnt = min(64, end - base);
        int sv = 0;
        u32 wx = 0, wy = 0;
        if (lane < cnt) {
            sv = csr_src[base + lane];
            float4 as4 = *(const float4*)&asrc[sv * 4];
            float e0 = as4.x + ad4.x; e0 = e0 > 0.f ? e0 : NEG_SLOPE * e0;
            float e1 = as4.y + ad4.y; e1 = e1 > 0.f ? e1 : NEG_SLOPE * e1;
            float e2 = as4.z + ad4.z; e2 = e2 > 0.f ? e2 : NEG_SLOPE * e2;
            float e3 = as4.w + ad4.w; e3 = e3 > 0.f ? e3 : NEG_SLOPE * e3;
            wx = (u32)f2bf(__expf(e0)) | ((u32)f2bf(__expf(e1)) << 16);
            wy = (u32)f2bf(__expf(e2)) | ((u32)f2bf(__expf(e3)) << 16);
        }
        int k = 0;
        for (; k + 3 < cnt; k += 4) {
            int s0 = __builtin_amdgcn_readlane(sv, k);
            int s1 = __builtin_amdgcn_readlane(sv, k + 1);
            int s2 = __builtin_amdgcn_readlane(sv, k + 2);
            int s3 = __builtin_amdgcn_readlane(sv, k + 3);
            u32 x0w = __builtin_amdgcn_readlane((int)wx, k), y0w = __builtin_amdgcn_readlane((int)wy, k);
            u32 x1w = __builtin_amdgcn_readlane((int)wx, k + 1), y1w = __builtin_amdgcn_readlane((int)wy, k + 1);
            u32 x2w = __builtin_amdgcn_readlane((int)wx, k + 2), y2w = __builtin_amdgcn_readlane((int)wy, k + 2);
            u32 x3w = __builtin_amdgcn_readlane((int)wx, k + 3), y3w = __builtin_amdgcn_readlane((int)wy, k + 3);
            ushort4 v0 = *(const ushort4*)&xhp[(size_t)s0 * HC + poff];
            ushort4 v1 = *(const ushort4*)&xhp[(size_t)s1 * HC + poff];
            ushort4 v2 = *(const ushort4*)&xhp[(size_t)s2 * HC + poff];
            ushort4 v3 = *(const ushort4*)&xhp[(size_t)s3 * HC + poff];
            float w0 = bf2f((u16)((hsel ? y0w : x0w) >> hsh));
            float w1 = bf2f((u16)((hsel ? y1w : x1w) >> hsh));
            float w2 = bf2f((u16)((hsel ? y2w : x2w) >> hsh));
            float w3 = bf2f((u16)((hsel ? y3w : x3w) >> hsh));
            den += (w0 + w1) + (w2 + w3);
            a0 += w0 * bf2f(v0.x) + w1 * bf2f(v1.x) + w2 * bf2f(v2.x) + w3 * bf2f(v3.x);
            a1 += w0 * bf2f(v0.y) + w1 * bf2f(v1.y) + w2 * bf2f(v2.y) + w3 * bf2f(v3.y);
            a2 += w0 * bf2f(v0.z) + w1 * bf2f(v1.z) + w2 * bf2f(v2.z) + w3 * bf2f(v3.z);
            a3 += w0 * bf2f(v0.w) + w1 * bf2f(v1.w) + w2 * bf2f(v2.w) + w3 * bf2f(v3.w);
        }
        for (; k < cnt; ++k) {
            int s0 = __builtin_amdgcn_readlane(sv, k);
            u32 x0w = __builtin_amdgcn_readlane((int)wx, k), y0w = __builtin_amdgcn_readlane((int)wy, k);
            ushort4 v0 = *(const ushort4*)&xhp[(size_t)s0 * HC + poff];
            float w0 = bf2f((u16)((hsel ? y0w : x0w) >> hsh));
            den += w0;
            a0 += w0 * bf2f(v0.x);
            a1 += w0 * bf2f(v0.y);
            a2 += w0 * bf2f(v0.z);
            a3 += w0 * bf2f(v0.w);
        }
    }
    float inv = 1.f / (den + 1e-16f);
    const int ch0 = h * 64 + c16;
    ushort4 o;
    o.x = f2bf(a0 * inv + bias[ch0 +  0]);
    o.y = f2bf(a1 * inv + bias[ch0 + 16]);
    o.z = f2bf(a2 * inv + bias[ch0 + 32]);
    o.w = f2bf(a3 * inv + bias[ch0 + 48]);
    *(ushort4*)&out[(size_t)d * HC + poff] = o;   // permuted, coalesced
}

// ---------------- BatchNorm stats over permuted buffer (positional) ----------------

__global__ __launch_bounds__(256)
void bn_stats_kernel(const u16* __restrict__ x, float* __restrict__ part) {
    const int tid = threadIdx.x;
    float s[8] = {}, s2[8] = {};
    const size_t total = (size_t)NNODES * HC;
    const size_t stride = (size_t)NB * 256 * 8;
    for (size_t f = ((size_t)blockIdx.x * 256 + tid) * 8; f < total; f += stride) {
        ushort8v v = *(const ushort8v*)&x[f];
#pragma unroll
        for (int i = 0; i < 8; ++i) {
            float t = bf2f(v[i]);
            s[i] += t;
            s2[i] += t * t;
        }
    }
#pragma unroll
    for (int i = 0; i < 8; ++i) {
        s[i] += __shfl_xor(s[i], 32, 64);
        s2[i] += __shfl_xor(s2[i], 32, 64);
    }
    __shared__ float red[4][512];
    const int wave = tid >> 6, lane = tid & 63;
    if (lane < 32) {
#pragma unroll
        for (int i = 0; i < 8; ++i) {
            red[wave][lane * 8 + i] = s[i];
            red[wave][256 + lane * 8 + i] = s2[i];
        }
    }
    __syncthreads();
    for (int j = tid; j < 512; j += 256)
        part[(size_t)blockIdx.x * 512 + j] = red[0][j] + red[1][j] + red[2][j] + red[3][j];
}

// ---------------- BN fold (permutation-aware) ----------------

__global__ __launch_bounds__(256)
void fold_kernel(const float* __restrict__ W, const float* __restrict__ part,
                 const float* __restrict__ g, const float* __restrict__ beta,
                 const float* __restrict__ baseBias,
                 u16* __restrict__ Wt, float* __restrict__ biasOut, int Ncols) {
    __shared__ float sh[256];
    __shared__ float stat2[2];
    const int b = blockIdx.x;
    const int tid = threadIdx.x;
    if (b < 256) {
        const int p = pos256(b);
        const int wave = tid >> 6, lane = tid & 63;
        if (wave < 2) {
            int off = wave * 256;
            float v = part[(size_t)lane * 512 + off + p] + part[(size_t)(lane + 64) * 512 + off + p];
#pragma unroll
            for (int o = 1; o <= 32; o <<= 1) v += __shfl_xor(v, o, 64);
            if (lane == 0) stat2[wave] = v;
        }
        __syncthreads();
        float mu = stat2[0] * (1.f / NNODES);
        float var = stat2[1] * (1.f / NNODES) - mu * mu;
        float rg = rsqrtf(var + BN_EPS) * g[b];
        for (int n = tid; n < Ncols; n += 256)
            Wt[n * 256 + p] = f2bf(W[b * Ncols + n] * rg);
    } else {
        const int p = pos256(tid);
        float sum = 0.f, sq = 0.f;
        for (int k = 0; k < NB; ++k) {
            sum += part[(size_t)k * 512 + p];
            sq += part[(size_t)k * 512 + 256 + p];
        }
        float mu = sum * (1.f / NNODES);
        float var = sq * (1.f / NNODES) - mu * mu;
        float rg = rsqrtf(var + BN_EPS) * g[tid];
        sh[tid] = beta[tid] - mu * rg;
        __syncthreads();
        if (tid < Ncols) {
            float acc = baseBias ? baseBias[tid] : 0.f;
            for (int k = 0; k < 256; ++k) acc += sh[k] * W[k * Ncols + tid];
            biasOut[tid] = acc;
        }
    }
}

// ---------------- fused final GEMM (M x 64, K=256) + bias + log_softmax ----------------

__global__ __launch_bounds__(256)
void final_ls_kernel(const u16* __restrict__ A, const u16* __restrict__ Bt,
                     const float* __restrict__ bias,
                     float* __restrict__ emb, float* __restrict__ out, int M) {
    __shared__ u16 As[128 * 32];
    __shared__ u16 Bs[64 * 32];
    const int tid = threadIdx.x;
    const int wave = tid >> 6, lane = tid & 63;
    const int q15 = lane & 15, quad = lane >> 4;
    const int rowBase = blockIdx.x * 128;

    floatx4 acc[2][4];
    floatx4 zero = {0.f, 0.f, 0.f, 0.f};
#pragma unroll
    for (int i = 0; i < 2; ++i)
#pragma unroll
        for (int j = 0; j < 4; ++j) acc[i][j] = zero;

    for (int kt = 0; kt < 256; kt += 32) {
#pragma unroll
        for (int rnd = 0; rnd < 2; ++rnd) {
            int slot = rnd * 256 + wave * 64 + lane;
            int r = slot >> 2;
            int c = (slot & 3) * 8;
            int ar = rowBase + r; if (ar >= M) ar = M - 1;
            async16(&As[(rnd * 256 + wave * 64) * 8], &A[(size_t)ar * 256 + kt + c]);
        }
        {
            int slot = wave * 64 + lane;
            int r = slot >> 2;
            int c = (slot & 3) * 8;
            async16(&Bs[(wave * 64) * 8], &Bt[(size_t)r * 256 + kt + c]);
        }
        __syncthreads();

        short8 af[2], bfr[4];
#pragma unroll
        for (int i = 0; i < 2; ++i)
            af[i] = *(const short8*)&As[(wave * 32 + i * 16 + q15) * 32 + quad * 8];
#pragma unroll
        for (int j = 0; j < 4; ++j)
            bfr[j] = *(const short8*)&Bs[(j * 16 + q15) * 32 + quad * 8];
#pragma unroll
        for (int i = 0; i < 2; ++i)
#pragma unroll
            for (int j = 0; j < 4; ++j)
                acc[i][j] = __builtin_amdgcn_mfma_f32_16x16x32_bf16(af[i], bfr[j], acc[i][j], 0, 0, 0);
        __syncthreads();
    }

#pragma unroll
    for (int i = 0; i < 2; ++i) {
#pragma unroll
        for (int rr = 0; rr < 4; ++rr) {
            float v[4];
#pragma unroll
            for (int j = 0; j < 4; ++j) v[j] = acc[i][j][rr] + bias[j * 16 + q15];
            float m = fmaxf(fmaxf(v[0], v[1]), fmaxf(v[2], v[3]));
#pragma unroll
            for (int off = 1; off <= 8; off <<= 1) m = fmaxf(m, __shfl_xor(m, off, 64));
            float s = __expf(v[0] - m) + __expf(v[1] - m) + __expf(v[2] - m) + __expf(v[3] - m);
#pragma unroll
            for (int off = 1; off <= 8; off <<= 1) s += __shfl_xor(s, off, 64);
            float ls = m + logf(s);
            int grow = rowBase + wave * 32 + i * 16 + quad * 4 + rr;
            if (grow < M) {
#pragma unroll
                for (int j = 0; j < 4; ++j) {
                    int col = j * 16 + q15;
                    emb[(size_t)grow * OUTDIM + col] = v[j];
                    out[(size_t)grow * OUTDIM + col] = v[j] - ls;
                }
            }
        }
    }
}

// ---------------- launch ----------------

extern "C" void kernel_launch(void* const* d_in, const int* in_sizes, int n_in,
                              void* d_out, int out_size, void* d_ws, size_t ws_size,
                              hipStream_t stream) {
    const float* x   = (const float*)d_in[0];
    const int*   ei  = (const int*)d_in[1];
    const float* W1  = (const float*)d_in[2];
    const float* at_s1 = (const float*)d_in[3];
    const float* at_d1 = (const float*)d_in[4];
    const float* b1  = (const float*)d_in[5];
    const float* W2  = (const float*)d_in[6];
    const float* at_s2 = (const float*)d_in[7];
    const float* at_d2 = (const float*)d_in[8];
    const float* b2  = (const float*)d_in[9];
    const float* g1  = (const float*)d_in[10];
    const float* be1 = (const float*)d_in[11];
    const float* g2  = (const float*)d_in[12];
    const float* be2 = (const float*)d_in[13];
    const float* Wl  = (const float*)d_in[14];
    const float* bl  = (const float*)d_in[15];

    float* out = (float*)d_out;                        // [N, 64] log_softmax
    float* emb = out + (size_t)NNODES * OUTDIM;        // [N, 64] emb

    char* ws = (char*)d_ws;
    size_t off = 0;
    auto alloc = [&](size_t bytes) {
        void* p = ws + off;
        off += (bytes + 255) & ~(size_t)255;
        return p;
    };
    int*   cnt     = (int*)alloc((size_t)NNODES * 4);
    int*   row_off = (int*)alloc((size_t)(NNODES + 1) * 4);
    int*   nxt     = (int*)alloc((size_t)NNODES * 4);
    int*   bsums   = (int*)alloc(64 * 4);
    int*   csr_src = (int*)alloc((size_t)ETOT * 4);
    float* asrc    = (float*)alloc((size_t)NNODES * 4 * 4);
    float* adst    = (float*)alloc((size_t)NNODES * 4 * 4);
    u16*   xhp     = (u16*)alloc((size_t)NNODES * HC * 2);   // permuted bf16 table
    u16*   ag_bf   = (u16*)alloc((size_t)NNODES * HC * 2);   // permuted aggregate
    u16*   w1t     = (u16*)alloc((size_t)HC * INDIM * 2);
    u16*   w2t     = (u16*)alloc((size_t)HC * HC * 2);
    u16*   wlt     = (u16*)alloc((size_t)OUTDIM * HC * 2);
    float* part    = (float*)alloc((size_t)NB * 512 * 4);
    float* bias2   = (float*)alloc(HC * 4);
    float* blp     = (float*)alloc(OUTDIM * 4);

    const int scanBlocks = (NNODES + 4095) / 4096;
    const int eBlocks = (ETOT + 255) / 256;

    // ---- CSR build ----
    hipMemsetAsync(cnt, 0, (size_t)NNODES * 4, stream);
    hist_kernel<<<eBlocks, 256, 0, stream>>>(ei, cnt);
    scan1_kernel<<<scanBlocks, 256, 0, stream>>>(cnt, row_off, bsums);
    scan2_kernel<<<scanBlocks, 256, 0, stream>>>(row_off, bsums, nxt);
    fill_csr_kernel<<<(FILL_S + 255) / 256, 256, 0, stream>>>(ei, nxt, csr_src);

    // ---- weight cast (layer-1 only; layer-2/final fold their own) ----
    wcast_kernel<<<(INDIM * HC + 255) / 256, 256, 0, stream>>>(W1, w1t, INDIM, HC);

    dim3 gemmGrid(2, (NNODES + 127) / 128);

    // ---- Layer 1 (fp32-A gemm + fused alpha + permuted bf16 table) ----
    gemm_gat_kernel<true><<<gemmGrid, 256, 0, stream>>>(x, w1t, nullptr, at_s1, at_d1,
                                                        xhp, asrc, adst, NNODES, INDIM);
    aggregate_kernel<<<NNODES / 4, 256, 0, stream>>>(row_off, csr_src, asrc, adst, xhp, b1, ag_bf);
    bn_stats_kernel<<<NB, 256, 0, stream>>>(ag_bf, part);
    fold_kernel<<<257, 256, 0, stream>>>(W2, part, g1, be1, nullptr, w2t, bias2, HC);

    // ---- Layer 2 (BN1 folded into W2/bias2; A permuted, Wt K-permuted to match) ----
    gemm_gat_kernel<false><<<gemmGrid, 256, 0, stream>>>(ag_bf, w2t, bias2, at_s2, at_d2,
                                                         xhp, asrc, adst, NNODES, HC);
    aggregate_kernel<<<NNODES / 4, 256, 0, stream>>>(row_off, csr_src, asrc, adst, xhp, b2, ag_bf);
    bn_stats_kernel<<<NB, 256, 0, stream>>>(ag_bf, part);
    fold_kernel<<<257, 256, 0, stream>>>(Wl, part, g2, be2, bl, wlt, blp, OUTDIM);

    // ---- Final linear (BN2 folded) + log_softmax, fused ----
    final_ls_kernel<<<(NNODES + 127) / 128, 256, 0, stream>>>(ag_bf, wlt, blp, emb, out, NNODES);
}